// Round 3
// baseline (74.302 us; speedup 1.0000x reference)
//
#include <hip/hip_runtime.h>

// YOLO loss: N=4096 images, S=14 grid, B=2 boxes, NC=20 classes.
// ncells = N*S*S = 802816 = 1568 blocks * 512 cells.
// R3: coalesced LDS staging of pred (kills 4x L1-transaction blowup of the
// 240B-stride dwordx4 pattern) + fused last-block-done finalize (kills one
// launch + chained-kernel latency).

#define GS 14
#define NCLS 20
#define BLOCK 256
#define CPT 2
#define CPB (BLOCK * CPT)          // 512 cells per block
#define SLAB_F4 (CPB * 30 / 4)     // 3840 float4 = 61440 B LDS

// ws layout:
//   ((int*)ws)[0]        : mask-format flag (0=int32, 1=uint8, 2=float32)
//   ((int*)ws)[8]        : block arrival counter (zeroed by init each call)
//   ws[64 + b*16 + k]    : block b's partial sums, k in {reg, contain, noobj, cls}
#define WS_PART 64

__global__ void yolo_init_kernel(const unsigned char* __restrict__ mask_bytes,
                                 int ncells, float* __restrict__ ws) {
    // sniff mask dtype: int32 -> nonzero bytes only at k%4==0, all <=1
    //                   uint8 -> nonzero bytes at k%4!=0, all <=1
    //                   float32 -> some byte > 1 (0x3f of 1.0f)
    __shared__ int s_nz_off, s_gt1;
    if (threadIdx.x == 0) { s_nz_off = 0; s_gt1 = 0; }
    __syncthreads();
    int nscan = 4096;
    if (ncells < nscan) nscan = ncells;
    for (int i = threadIdx.x; i < nscan; i += blockDim.x) {
        unsigned char v = mask_bytes[i];
        if (v > 1) s_gt1 = 1;
        if ((i & 3) != 0 && v != 0) s_nz_off = 1;
    }
    __syncthreads();
    if (threadIdx.x == 0) {
        ((int*)ws)[0] = s_gt1 ? 2 : (s_nz_off ? 1 : 0);
        ((int*)ws)[8] = 0;
    }
}

__device__ __forceinline__ void cell_compute(const float* __restrict__ lv,
                                             const float* __restrict__ tbox,
                                             const float* __restrict__ tcls,
                                             int cell, bool m,
                                             float& reg, float& cont,
                                             float& noobj, float& cls) {
    const float invS = 1.0f / (float)GS;
    if (m) {
        const float4 tb4 = *reinterpret_cast<const float4*>(tbox + (size_t)cell * 4);
        const float tx = tb4.x, ty = tb4.y, tw = tb4.z, th = tb4.w;

        const float tcx = tx * invS, tcy = ty * invS;
        const float t_x1 = tcx - 0.5f * tw, t_y1 = tcy - 0.5f * th;
        const float t_x2 = tcx + 0.5f * tw, t_y2 = tcy + 0.5f * th;
        const float ta = (t_x2 - t_x1) * (t_y2 - t_y1);

        const float b0x = lv[0], b0y = lv[1], b0w = lv[2], b0h = lv[3], b0c = lv[4];
        const float b1x = lv[5], b1y = lv[6], b1w = lv[7], b1h = lv[8], b1c = lv[9];

        float iou0, iou1;
        {
            const float cx = b0x * invS, cy = b0y * invS;
            const float x1 = cx - 0.5f * b0w, y1 = cy - 0.5f * b0h;
            const float x2 = cx + 0.5f * b0w, y2 = cy + 0.5f * b0h;
            const float iw = fmaxf(fminf(x2, t_x2) - fmaxf(x1, t_x1), 0.0f);
            const float ih = fmaxf(fminf(y2, t_y2) - fmaxf(y1, t_y1), 0.0f);
            const float inter = iw * ih;
            const float pa = (x2 - x1) * (y2 - y1);
            iou0 = inter / (pa + ta - inter);
        }
        {
            const float cx = b1x * invS, cy = b1y * invS;
            const float x1 = cx - 0.5f * b1w, y1 = cy - 0.5f * b1h;
            const float x2 = cx + 0.5f * b1w, y2 = cy + 0.5f * b1h;
            const float iw = fmaxf(fminf(x2, t_x2) - fmaxf(x1, t_x1), 0.0f);
            const float ih = fmaxf(fminf(y2, t_y2) - fmaxf(y1, t_y1), 0.0f);
            const float inter = iw * ih;
            const float pa = (x2 - x1) * (y2 - y1);
            iou1 = inter / (pa + ta - inter);
        }

        const bool sel1 = iou1 > iou0;   // jnp.argmax: first max wins -> strict >
        const float biou = fmaxf(iou0, iou1);
        const float rx = sel1 ? b1x : b0x;
        const float ry = sel1 ? b1y : b0y;
        const float rw = sel1 ? b1w : b0w;
        const float rh = sel1 ? b1h : b0h;
        const float rc = sel1 ? b1c : b0c;

        const float d0 = rx - tx, d1 = ry - ty;
        const float d2 = sqrtf(rw) - sqrtf(tw);
        const float d3 = sqrtf(rh) - sqrtf(th);
        reg += d0 * d0 + d1 * d1 + d2 * d2 + d3 * d3;

        const float dc = rc - biou;
        cont += dc * dc;

        // tcls row: 80 B, 16B-aligned -> 5 explicit float4 loads
        const float4* tc4 = reinterpret_cast<const float4*>(tcls + (size_t)cell * NCLS);
        float csum = 0.0f;
        #pragma unroll
        for (int j = 0; j < 5; ++j) {
            const float4 t4 = tc4[j];
            float d;
            d = lv[10 + j * 4 + 0] - t4.x; csum += d * d;
            d = lv[10 + j * 4 + 1] - t4.y; csum += d * d;
            d = lv[10 + j * 4 + 2] - t4.z; csum += d * d;
            d = lv[10 + j * 4 + 3] - t4.w; csum += d * d;
        }
        cls += csum;
    } else {
        const float c0 = lv[4], c1 = lv[9];
        noobj += c0 * c0 + c1 * c1;
    }
}

__launch_bounds__(BLOCK)
__global__ void yolo_loss_kernel(const float* __restrict__ pred,
                                 const float* __restrict__ tbox,
                                 const float* __restrict__ tcls,
                                 const void* __restrict__ mask,
                                 float* __restrict__ ws,
                                 int ncells, float inv_n,
                                 float* __restrict__ out) {
    __shared__ float4 slab4[SLAB_F4];   // 61440 B: this block's 512 pred rows
    __shared__ float sred[4][4];
    __shared__ int s_last;

    const int fmt = ((const int*)ws)[0];
    const int tid = threadIdx.x;
    const int block_base = blockIdx.x * CPB;

    float reg = 0.0f, cont = 0.0f, noobj = 0.0f, cls = 0.0f;

    if (block_base + CPB <= ncells) {
        // mask first (independent, latency hidden under staging)
        const int g = blockIdx.x * BLOCK + tid;
        bool m0, m1;
        if (fmt == 2) {
            const float2 mm = reinterpret_cast<const float2*>(mask)[g];
            m0 = mm.x != 0.0f; m1 = mm.y != 0.0f;
        } else if (fmt == 1) {
            const uchar2 mm = reinterpret_cast<const uchar2*>(mask)[g];
            m0 = mm.x != 0; m1 = mm.y != 0;
        } else {
            const int2 mm = reinterpret_cast<const int2*>(mask)[g];
            m0 = mm.x != 0; m1 = mm.y != 0;
        }

        // coalesced staging: 15 iterations, thread t loads slab f4 i*256+t
        const float4* src = reinterpret_cast<const float4*>(pred) + (size_t)blockIdx.x * SLAB_F4;
        #pragma unroll
        for (int i = 0; i < 15; ++i)
            slab4[i * BLOCK + tid] = src[i * BLOCK + tid];
        __syncthreads();

        const float* lv = reinterpret_cast<const float*>(slab4) + tid * 60;
        cell_compute(lv,      tbox, tcls, block_base + tid * 2,     m0, reg, cont, noobj, cls);
        cell_compute(lv + 30, tbox, tcls, block_base + tid * 2 + 1, m1, reg, cont, noobj, cls);
    } else {
        // generic tail (not hit for ncells = 802816)
        for (int cell = block_base + tid; cell < ncells; cell += BLOCK) {
            bool m;
            if (fmt == 2)      m = ((const float*)mask)[cell] != 0.0f;
            else if (fmt == 1) m = ((const unsigned char*)mask)[cell] != 0;
            else               m = ((const int*)mask)[cell] != 0;
            float v[30];
            #pragma unroll
            for (int f = 0; f < 30; ++f) v[f] = pred[(size_t)cell * 30 + f];
            cell_compute(v, tbox, tcls, cell, m, reg, cont, noobj, cls);
        }
        __syncthreads();   // keep barrier count uniform (all blocks hit one)
    }

    // wave64 reduce
    #pragma unroll
    for (int off = 32; off > 0; off >>= 1) {
        reg   += __shfl_down(reg, off);
        cont  += __shfl_down(cont, off);
        noobj += __shfl_down(noobj, off);
        cls   += __shfl_down(cls, off);
    }
    const int wave = tid >> 6;
    if ((tid & 63) == 0) {
        sred[wave][0] = reg; sred[wave][1] = cont;
        sred[wave][2] = noobj; sred[wave][3] = cls;
    }
    __syncthreads();

    if (tid == 0) {
        float r = 0, c = 0, no = 0, cl = 0;
        #pragma unroll
        for (int w = 0; w < 4; ++w) {
            r += sred[w][0]; c += sred[w][1]; no += sred[w][2]; cl += sred[w][3];
        }
        float4* slot = reinterpret_cast<float4*>(ws + WS_PART + (size_t)blockIdx.x * 16);
        *slot = make_float4(r, c, no, cl);
        __threadfence();                         // publish partial before arrival
        int prev = atomicAdd((int*)ws + 8, 1);
        s_last = (prev == (int)gridDim.x - 1);
    }
    __syncthreads();

    if (s_last) {
        // last block: reduce all per-block partials and write the output
        __threadfence();                         // acquire: see others' partials
        float r = 0, c = 0, no = 0, cl = 0;
        for (int b = tid; b < (int)gridDim.x; b += BLOCK) {
            const float4 p = *reinterpret_cast<const float4*>(ws + WS_PART + (size_t)b * 16);
            r += p.x; c += p.y; no += p.z; cl += p.w;
        }
        #pragma unroll
        for (int off = 32; off > 0; off >>= 1) {
            r  += __shfl_down(r, off);
            c  += __shfl_down(c, off);
            no += __shfl_down(no, off);
            cl += __shfl_down(cl, off);
        }
        if ((tid & 63) == 0) {
            sred[wave][0] = r; sred[wave][1] = c;
            sred[wave][2] = no; sred[wave][3] = cl;
        }
        __syncthreads();
        if (tid == 0) {
            float R = 0, C = 0, NO = 0, CL = 0;
            #pragma unroll
            for (int w = 0; w < 4; ++w) {
                R += sred[w][0]; C += sred[w][1]; NO += sred[w][2]; CL += sred[w][3];
            }
            const float total = (5.0f * R + 0.5f * NO + C + CL) * inv_n;
            out[0] = total;
            out[1] = R;
            out[2] = C;
            out[3] = NO;
            out[4] = CL;
        }
    }
}

extern "C" void kernel_launch(void* const* d_in, const int* in_sizes, int n_in,
                              void* d_out, int out_size, void* d_ws, size_t ws_size,
                              hipStream_t stream) {
    const float* pred = (const float*)d_in[0];
    const float* tbox = (const float*)d_in[1];
    const float* tcls = (const float*)d_in[2];
    const void*  mask = d_in[3];
    float* ws  = (float*)d_ws;
    float* out = (float*)d_out;

    const int ncells = in_sizes[3];                 // N * S * S
    const int n_img  = ncells / (GS * GS);          // N
    const float inv_n = 1.0f / (float)n_img;

    yolo_init_kernel<<<1, 256, 0, stream>>>((const unsigned char*)mask, ncells, ws);

    const int grid = (ncells + CPB - 1) / CPB;      // 1568
    yolo_loss_kernel<<<grid, BLOCK, 0, stream>>>(pred, tbox, tcls, mask, ws,
                                                 ncells, inv_n, out);
}